// Round 6
// baseline (1306.444 us; speedup 1.0000x reference)
//
#include <hip/hip_runtime.h>
#include <hip/hip_fp16.h>

#define B_SZ 4
#define T_SEQ 2048
#define NH 16
#define HD 64
#define DMODEL 1024
#define MTOT (B_SZ * T_SEQ)   // 8192

typedef __bf16 bf16x8 __attribute__((ext_vector_type(8)));
typedef float f32x4 __attribute__((ext_vector_type(4)));
typedef _Float16 f16x4 __attribute__((ext_vector_type(4)));

__device__ __forceinline__ unsigned short f2bf(float f) {
    union { float f; unsigned int i; } c; c.f = f;
    unsigned int u = c.i;
    u += 0x7fffu + ((u >> 16) & 1u);   // round-to-nearest-even
    return (unsigned short)(u >> 16);
}
__device__ __forceinline__ float sigm(float x) { return 1.f / (1.f + __expf(-x)); }

// async global->LDS DMA, 16B/lane; LDS dest = wave-uniform base + lane*16
__device__ __forceinline__ void dma16(const void* g, void* l) {
    __builtin_amdgcn_global_load_lds(
        (const __attribute__((address_space(1))) void*)g,
        (__attribute__((address_space(3))) void*)l, 16, 0, 0);
}

// DPP row_ror butterfly: 4 stages -> every lane of a 16-lane row holds the row sum.
template <int CTRL>
__device__ __forceinline__ float dppadd(float x) {
    int v = __builtin_amdgcn_update_dpp(0, __builtin_bit_cast(int, x), CTRL, 0xf, 0xf, false);
    return x + __builtin_bit_cast(float, v);
}
__device__ __forceinline__ float rowsum16(float x) {
    x = dppadd<0x128>(x);
    x = dppadd<0x124>(x);
    x = dppadd<0x122>(x);
    x = dppadd<0x121>(x);
    return x;
}

// ---------------------------------------------------------------- LayerNorm
__global__ __launch_bounds__(256, 1) void k_ln(const float* __restrict__ x,
                                               const float* __restrict__ lnw,
                                               const float* __restrict__ lnb,
                                               unsigned short* __restrict__ xn) {
    const int m = blockIdx.x;
    const int t = threadIdx.x;
    float4 xv = ((const float4*)(x + (size_t)m * DMODEL))[t];
    float s = xv.x + xv.y + xv.z + xv.w;
    float s2 = xv.x * xv.x + xv.y * xv.y + xv.z * xv.z + xv.w * xv.w;
#pragma unroll
    for (int off = 32; off >= 1; off >>= 1) {
        s += __shfl_xor(s, off);
        s2 += __shfl_xor(s2, off);
    }
    __shared__ float red[8];
    const int wid = t >> 6;
    if ((t & 63) == 0) { red[wid] = s; red[4 + wid] = s2; }
    __syncthreads();
    if (t == 0) {
        float su = red[0] + red[1] + red[2] + red[3];
        float sq = red[4] + red[5] + red[6] + red[7];
        float mu = su * (1.f / DMODEL);
        float var = sq * (1.f / DMODEL) - mu * mu;
        red[0] = mu;
        red[1] = rsqrtf(var + 1e-5f);
    }
    __syncthreads();
    float mu = red[0], rstd = red[1];
    float4 w4 = ((const float4*)lnw)[t];
    float4 b4 = ((const float4*)lnb)[t];
    ushort4 o;
    o.x = f2bf((xv.x - mu) * rstd * w4.x + b4.x);
    o.y = f2bf((xv.y - mu) * rstd * w4.y + b4.y);
    o.z = f2bf((xv.z - mu) * rstd * w4.z + b4.z);
    o.w = f2bf((xv.w - mu) * rstd * w4.w + b4.w);
    ((ushort4*)(xn + (size_t)m * DMODEL))[t] = o;
}

// ------------------------------------------- fp32 -> bf16 weight conversion
struct WPtrs { const float* p0; const float* p1; const float* p2; const float* p3; const float* p4; };

__global__ __launch_bounds__(256, 1) void k_wconv(WPtrs w, unsigned short* __restrict__ dst) {
    const int plane = blockIdx.y;
    const float* src = plane == 0 ? w.p0 : plane == 1 ? w.p1 : plane == 2 ? w.p2
                                                             : plane == 3 ? w.p3 : w.p4;
    const size_t i = ((size_t)blockIdx.x * 256 + threadIdx.x) * 8;
    float4 f0 = *(const float4*)(src + i);
    float4 f1 = *(const float4*)(src + i + 4);
    uint4 o;
    o.x = (unsigned)f2bf(f0.x) | ((unsigned)f2bf(f0.y) << 16);
    o.y = (unsigned)f2bf(f0.z) | ((unsigned)f2bf(f0.w) << 16);
    o.z = (unsigned)f2bf(f1.x) | ((unsigned)f2bf(f1.y) << 16);
    o.w = (unsigned)f2bf(f1.z) | ((unsigned)f2bf(f1.w) << 16);
    *(uint4*)(dst + (size_t)plane * 1048576 + i) = o;
}

__global__ __launch_bounds__(256, 1) void k_cvt1(const float* __restrict__ src,
                                                 unsigned short* __restrict__ dst) {
    const size_t i = ((size_t)blockIdx.x * 256 + threadIdx.x) * 8;
    float4 f0 = *(const float4*)(src + i);
    float4 f1 = *(const float4*)(src + i + 4);
    uint4 o;
    o.x = (unsigned)f2bf(f0.x) | ((unsigned)f2bf(f0.y) << 16);
    o.y = (unsigned)f2bf(f0.z) | ((unsigned)f2bf(f0.w) << 16);
    o.z = (unsigned)f2bf(f1.x) | ((unsigned)f2bf(f1.y) << 16);
    o.w = (unsigned)f2bf(f1.z) | ((unsigned)f2bf(f1.w) << 16);
    *(uint4*)(dst + i) = o;
}

// ------------------------------------------------- 128x128 bf16 MFMA tile GEMM
template <int KDIM>
__device__ __forceinline__ void gemm128(const unsigned short* __restrict__ A,
                                        const unsigned short* __restrict__ Bw,
                                        int m0, int n0, f32x4 acc[4][4]) {
    __shared__ __align__(16) unsigned short sA[128 * 32];
    __shared__ __align__(16) unsigned short sB[128 * 32];

    const int t = threadIdx.x;
    const int lane = t & 63;
    const int wv = t >> 6;
    const int wm = wv >> 1, wn = wv & 1;
    const int ml = lane & 15, kq = lane >> 4;

#pragma unroll
    for (int i = 0; i < 4; i++)
#pragma unroll
        for (int j = 0; j < 4; j++) {
            f32x4 z; z[0] = 0.f; z[1] = 0.f; z[2] = 0.f; z[3] = 0.f;
            acc[i][j] = z;
        }

    const unsigned short* pA = A + (size_t)m0 * KDIM;
    const unsigned short* pB = Bw + (size_t)n0 * KDIM;
    const unsigned short* gA0 = pA + (size_t)(t >> 2) * KDIM + (t & 3) * 8;
    const unsigned short* gA1 = gA0 + (size_t)64 * KDIM;
    const unsigned short* gB0 = pB + (size_t)(t >> 2) * KDIM + (t & 3) * 8;
    const unsigned short* gB1 = gB0 + (size_t)64 * KDIM;
    unsigned short* lA0 = sA + wv * 512;
    unsigned short* lA1 = lA0 + 2048;
    unsigned short* lB0 = sB + wv * 512;
    unsigned short* lB1 = lB0 + 2048;

    for (int kb = 0; kb < KDIM / 32; kb++) {
        const int ko = kb * 32;
        dma16(gA0 + ko, lA0);
        dma16(gA1 + ko, lA1);
        dma16(gB0 + ko, lB0);
        dma16(gB1 + ko, lB1);
        __syncthreads();
        bf16x8 af[4], bfr[4];
#pragma unroll
        for (int mt = 0; mt < 4; mt++)
            af[mt] = *(const bf16x8*)&sA[(wm * 64 + mt * 16 + ml) * 32 + kq * 8];
#pragma unroll
        for (int nt = 0; nt < 4; nt++)
            bfr[nt] = *(const bf16x8*)&sB[(wn * 64 + nt * 16 + ml) * 32 + kq * 8];
#pragma unroll
        for (int mt = 0; mt < 4; mt++)
#pragma unroll
            for (int nt = 0; nt < 4; nt++)
                acc[mt][nt] = __builtin_amdgcn_mfma_f32_16x16x32_bf16(af[mt], bfr[nt], acc[mt][nt], 0, 0, 0);
        __syncthreads();
    }
}

// -------------------------------------------- fused 5-way projection GEMM
// Writes into packed scan-input layout:
//   packA[bh][t][256] fp16 = [kn 0..63 | a 64..127 | aR 128..191 | q 192..255]
//   packB[(bh*4+cg)*2048+t] 64B = [v[cg*16..+15] fp16 | beta f32 | gamma f32 | pad]
__global__ __launch_bounds__(256, 1) void k_proj(const unsigned short* __restrict__ xn,
                                                 const unsigned short* __restrict__ wbf,
                                                 const float* __restrict__ ba,
                                                 const float* __restrict__ baR,
                                                 __half* __restrict__ packA,
                                                 __half* __restrict__ packB) {
    const int m0 = blockIdx.x * 128;
    const int yt = blockIdx.y;
    const int widx = yt >> 3;
    const int n0 = (yt & 7) * 128;
    const unsigned short* W = wbf + (size_t)widx * 1048576;
    f32x4 acc[4][4];
    gemm128<1024>(xn, W, m0, n0, acc);

    const float* bias = (widx == 3) ? ba : (widx == 4) ? baR : (const float*)0;
    const int arr = widx == 1 ? 0 : widx == 3 ? 1 : widx == 4 ? 2 : 3;  // k,a,aR,q
    const int lane = threadIdx.x & 63;
    const int wv = threadIdx.x >> 6;
    const int wm = wv >> 1, wn = wv & 1;
    const int ml = lane & 15, kq = lane >> 4;
#pragma unroll
    for (int mt = 0; mt < 4; mt++)
#pragma unroll
        for (int nt = 0; nt < 4; nt++) {
            const int rowg = m0 + wm * 64 + mt * 16 + kq * 4;
            const int colg = n0 + wn * 64 + nt * 16 + ml;
            float bval = bias ? bias[colg] : 0.f;
            const int h = colg >> 6, d = colg & 63;
#pragma unroll
            for (int r = 0; r < 4; r++) {
                float v = acc[mt][nt][r];
                if (widx >= 3) v = sigm(v + bval);
                const int m = rowg + r;
                const int b = m >> 11, tt = m & 2047;
                const size_t bh = (size_t)b * 16 + h;
                if (widx == 2) {
                    const size_t rec = (bh * 4 + (d >> 4)) * 2048 + tt;
                    packB[rec * 32 + (d & 15)] = __float2half(v);
                } else {
                    packA[(bh * 2048 + tt) * 256 + arr * 64 + d] = __float2half(v);
                }
            }
        }
}

// --------------------------------------------------- beta/gamma skinny GEMM
__global__ __launch_bounds__(256, 1) void k_bg(const unsigned short* __restrict__ xn,
                                               const float* __restrict__ Wb,
                                               const float* __restrict__ bb,
                                               const float* __restrict__ Wg,
                                               const float* __restrict__ bgp,
                                               __half* __restrict__ packB) {
    const int m = blockIdx.x;
    const int t = threadIdx.x;
    const int h = t >> 4, seg = t & 15;
    const ushort4* xr = (const ushort4*)(xn + (size_t)m * DMODEL + seg * 64);
    const float4* wbr = (const float4*)(Wb + (size_t)h * DMODEL + seg * 64);
    const float4* wgr = (const float4*)(Wg + (size_t)h * DMODEL + seg * 64);
    float db = 0.f, dg = 0.f;
#pragma unroll
    for (int u = 0; u < 16; u++) {
        ushort4 a = xr[u];
        float4 w1 = wbr[u], w2 = wgr[u];
        union { unsigned int i; float f; } c0, c1, c2, c3;
        c0.i = ((unsigned int)a.x) << 16; c1.i = ((unsigned int)a.y) << 16;
        c2.i = ((unsigned int)a.z) << 16; c3.i = ((unsigned int)a.w) << 16;
        db += c0.f * w1.x + c1.f * w1.y + c2.f * w1.z + c3.f * w1.w;
        dg += c0.f * w2.x + c1.f * w2.y + c2.f * w2.z + c3.f * w2.w;
    }
#pragma unroll
    for (int off = 1; off < 16; off <<= 1) {
        db += __shfl_xor(db, off);
        dg += __shfl_xor(dg, off);
    }
    if (seg == 0) {
        float2 bg2;
        bg2.x = sigm(db + bb[h]);
        bg2.y = sigm(dg + bgp[h]);
        const int b = m >> 11, tt = m & 2047;
        const size_t base = (((size_t)b * 16 + h) * 4) * 2048 + tt;
#pragma unroll
        for (int cg = 0; cg < 4; cg++)
            *(float2*)(packB + (base + (size_t)cg * 2048) * 32 + 16) = bg2;
    }
}

// ------------------------------------------- k normalization in packA (fp16)
__global__ __launch_bounds__(256, 1) void k_prep(__half* __restrict__ packA) {
    const int row = blockIdx.x * 16 + (threadIdx.x >> 4);  // bh*2048+t, 0..131071
    const int tr = threadIdx.x & 15;
    const size_t idx = (size_t)row * 256 + tr * 4;   // k at record offset 0
    f16x4 k4 = *(const f16x4*)(packA + idx);
    float k0 = (float)k4[0], k1 = (float)k4[1], k2 = (float)k4[2], k3 = (float)k4[3];
    float ss = k0 * k0 + k1 * k1 + k2 * k2 + k3 * k3;
    ss = rowsum16(ss);
    float inv = 1.f / fmaxf(sqrtf(ss), 1e-12f);
    f16x4 o;
    o[0] = (_Float16)(k0 * inv); o[1] = (_Float16)(k1 * inv);
    o[2] = (_Float16)(k2 * inv); o[3] = (_Float16)(k3 * inv);
    *(f16x4*)(packA + idx) = o;
}

// ------------------------------------------------------------- the scan
// 256 blocks = 64 (b,h) x 4 col-groups; 256 thr = 16 cols x 16 lanes (4 waves).
// Per-wave LDS rings fed by global_load_lds DMA (unsinkable) + hand vmcnt:
//   A-ring: 4 slots x 1KB (= 8 steps of [kn|a|aR|q] 512B)
//   B-ring: 2 slots x 1KB (= 32 steps of [v16|beta|gamma] 64B)
// No barriers anywhere; steady-state wait = s_waitcnt vmcnt(8).
__global__ __launch_bounds__(256, 1) void k_scan(const char* __restrict__ packA,
                                                 const char* __restrict__ packB,
                                                 unsigned short* __restrict__ ob) {
    __shared__ __align__(16) char lds[4 * 6144];

    const int blk = blockIdx.x;
    const int bh = blk >> 2, cg = blk & 3;
    const int b = bh >> 4, h = bh & 15;
    const int t = threadIdx.x;
    const int w = t >> 6;
    const int lane = t & 63;
    const int colb = t >> 4;      // 0..15 col within block
    const int tr = t & 15;
    const int j0 = tr * 4;
    const int ii = cg * 16 + colb;

    const size_t vbase = ((size_t)b * T_SEQ) * DMODEL + h * 64 + ii;
    char* myl = lds + w * 6144;
    const char* srcA = packA + (size_t)bh * 2048 * 512 + (size_t)lane * 16;
    const char* srcB = packB + (size_t)(bh * 4 + cg) * 2048 * 64 + (size_t)lane * 16;

    // preload: A pairs 0,1,2 (steps 0..5), B block 0 (steps 0..15)
    dma16(srcA + 0, myl + 0);
    dma16(srcA + 1024, myl + 1024);
    dma16(srcA + 2048, myl + 2048);
    dma16(srcB + 0, myl + 4096);
    asm volatile("s_waitcnt vmcnt(0)" ::: "memory");

    float S0 = 0, S1 = 0, S2 = 0, S3 = 0, R0 = 0, R1 = 0, R2 = 0, R3 = 0;

    auto body = [&](int s) {
        const __half* As = (const __half*)(myl + ((s >> 1) & 3) * 1024 + (s & 1) * 512);
        const char* Bs = myl + 4096 + ((s >> 4) & 1) * 1024 + (s & 15) * 64;
        f16x4 k4 = *(const f16x4*)(As + j0);
        f16x4 a4 = *(const f16x4*)(As + 64 + j0);
        f16x4 x4 = *(const f16x4*)(As + 128 + j0);
        f16x4 q4 = *(const f16x4*)(As + 192 + j0);
        float vc = (float)*((const __half*)Bs + colb);
        float2 bg2 = *(const float2*)(Bs + 32);

        const float kn0 = (float)k4[0], kn1 = (float)k4[1], kn2 = (float)k4[2], kn3 = (float)k4[3];
        const float a0 = (float)a4[0], a1 = (float)a4[1], a2 = (float)a4[2], a3 = (float)a4[3];
        const float x0 = (float)x4[0], x1 = (float)x4[1], x2 = (float)x4[2], x3 = (float)x4[3];

        float pred = S0 * kn0 + S1 * kn1 + S2 * kn2 + S3 * kn3;
        float Sd0 = a0 * S0, Sd1 = a1 * S1, Sd2 = a2 * S2, Sd3 = a3 * S3;
        float Rd0 = x0 * R0, Rd1 = x1 * R1, Rd2 = x2 * R2, Rd3 = x3 * R3;
        float kp = Sd0 * kn0 + Sd1 * kn1 + Sd2 * kn2 + Sd3 * kn3;
        float kpR = Rd0 * kn0 + Rd1 * kn1 + Rd2 * kn2 + Rd3 * kn3;
        pred = rowsum16(pred);
        kp = rowsum16(kp);
        kpR = rowsum16(kpR);
        const float rres = fminf(fmaxf(vc - pred, -1.f), 1.f);
        const float cS = bg2.x * (vc - kp);
        const float cR = bg2.y * (rres - kpR);
        S0 = fmaf(cS, kn0, Sd0); S1 = fmaf(cS, kn1, Sd1);
        S2 = fmaf(cS, kn2, Sd2); S3 = fmaf(cS, kn3, Sd3);
        R0 = fmaf(cR, kn0, Rd0); R1 = fmaf(cR, kn1, Rd1);
        R2 = fmaf(cR, kn2, Rd2); R3 = fmaf(cR, kn3, Rd3);
        float o = (S0 + R0) * (float)q4[0] + (S1 + R1) * (float)q4[1] +
                  (S2 + R2) * (float)q4[2] + (S3 + R3) * (float)q4[3];
        o = rowsum16(o);
        if (tr == 0)
            ob[vbase + (size_t)s * DMODEL] = f2bf(o);
    };

    for (int s = 0; s < T_SEQ; s += 2) {
        // steady-state wait: target = A-DMA for pair s/2, issued 3 iterations ago;
        // newer ops = 6 stores + 2 A-DMA (+<=1 B-DMA) -> vmcnt(8)
        asm volatile("s_waitcnt vmcnt(8)" ::: "memory");
        dma16(srcA + (size_t)((s + 6) & 2047) * 512, myl + (((s >> 1) + 3) & 3) * 1024);
        if ((s & 15) == 6)
            dma16(srcB + (size_t)((s + 10) & 2047) * 64, myl + 4096 + (((s >> 4) + 1) & 1) * 1024);
        body(s);
        body(s + 1);
    }
}

// ---------------------------------------------------- output GEMM + residual
__global__ __launch_bounds__(256, 1) void k_out(const unsigned short* __restrict__ ob,
                                                const unsigned short* __restrict__ wobf,
                                                const float* __restrict__ x,
                                                float* __restrict__ out) {
    const int m0 = blockIdx.x * 128;
    const int n0 = blockIdx.y * 128;
    f32x4 acc[4][4];
    gemm128<1024>(ob, wobf, m0, n0, acc);
    const int lane = threadIdx.x & 63;
    const int wv = threadIdx.x >> 6;
    const int wm = wv >> 1, wn = wv & 1;
    const int ml = lane & 15, kq = lane >> 4;
#pragma unroll
    for (int mt = 0; mt < 4; mt++)
#pragma unroll
        for (int nt = 0; nt < 4; nt++) {
            const int rowg = m0 + wm * 64 + mt * 16 + kq * 4;
            const int colg = n0 + wn * 64 + nt * 16 + ml;
#pragma unroll
            for (int r = 0; r < 4; r++) {
                size_t idx = (size_t)(rowg + r) * DMODEL + colg;
                out[idx] = acc[mt][nt][r] + x[idx];
            }
        }
}

extern "C" void kernel_launch(void* const* d_in, const int* in_sizes, int n_in,
                              void* d_out, int out_size, void* d_ws, size_t ws_size,
                              hipStream_t stream) {
    const float* x = (const float*)d_in[0];
    const float* Wq = (const float*)d_in[1];
    const float* Wk = (const float*)d_in[2];
    const float* Wv = (const float*)d_in[3];
    const float* Wa = (const float*)d_in[4];
    const float* ba = (const float*)d_in[5];
    const float* Wb = (const float*)d_in[6];
    const float* bb = (const float*)d_in[7];
    const float* Wg = (const float*)d_in[8];
    const float* bg = (const float*)d_in[9];
    const float* WaR = (const float*)d_in[10];
    const float* baR = (const float*)d_in[11];
    const float* Wo = (const float*)d_in[12];
    const float* lnw = (const float*)d_in[13];
    const float* lnb = (const float*)d_in[14];

    const size_t MB = 1048576ULL;
    const size_t packA_off = 0;              // 64 MB: [bh][t][512B]
    const size_t packB_off = 64 * MB;        // 32 MB: [bh*4+cg][t][64B]
    const size_t xn_off = 96 * MB;           // 16 MB: bf16 xn, reused for o
    const size_t wobf_off = 112 * MB;        // 2 MB: Wo bf16
    const size_t need = 114 * MB;
    if (ws_size < need) return;

    char* ws = (char*)d_ws;
    __half* packA = (__half*)(ws + packA_off);
    __half* packB = (__half*)(ws + packB_off);
    unsigned short* xn = (unsigned short*)(ws + xn_off);
    unsigned short* wobf = (unsigned short*)(ws + wobf_off);
    // d_out doubles as scratch for bf16 projection weights (10 MB of 32 MB);
    // only read by k_proj, fully overwritten by k_out at the end.
    unsigned short* wbf = (unsigned short*)d_out;

    WPtrs wp{Wq, Wk, Wv, Wa, WaR};
    k_wconv<<<dim3(512, 5), dim3(256), 0, stream>>>(wp, wbf);
    k_cvt1<<<dim3(512), dim3(256), 0, stream>>>(Wo, wobf);
    k_ln<<<dim3(MTOT), dim3(256), 0, stream>>>(x, lnw, lnb, xn);
    k_proj<<<dim3(64, 40), dim3(256), 0, stream>>>(xn, wbf, ba, baR, packA, packB);
    k_bg<<<dim3(MTOT), dim3(256), 0, stream>>>(xn, Wb, bb, Wg, bg, packB);
    k_prep<<<dim3(MTOT * NH / 16), dim3(256), 0, stream>>>(packA);
    // scan writes o (bf16) over xn (xn dead after k_proj/k_bg)
    k_scan<<<dim3(256), dim3(256), 0, stream>>>((const char*)packA, (const char*)packB, xn);
    k_out<<<dim3(64, 8), dim3(256), 0, stream>>>(xn, wobf, x, (float*)d_out);
}

// Round 8
// 944.412 us; speedup vs baseline: 1.3833x; 1.3833x over previous
//
#include <hip/hip_runtime.h>
#include <hip/hip_fp16.h>

#define B_SZ 4
#define T_SEQ 2048
#define NH 16
#define HD 64
#define DMODEL 1024
#define MTOT (B_SZ * T_SEQ)   // 8192

typedef __bf16 bf16x8 __attribute__((ext_vector_type(8)));
typedef float f32x4 __attribute__((ext_vector_type(4)));
typedef float f32x2 __attribute__((ext_vector_type(2)));
typedef _Float16 f16x4 __attribute__((ext_vector_type(4)));

__device__ __forceinline__ unsigned short f2bf(float f) {
    union { float f; unsigned int i; } c; c.f = f;
    unsigned int u = c.i;
    u += 0x7fffu + ((u >> 16) & 1u);   // round-to-nearest-even
    return (unsigned short)(u >> 16);
}
__device__ __forceinline__ float sigm(float x) { return 1.f / (1.f + __expf(-x)); }

// async global->LDS DMA, 16B/lane (GEMM staging only)
__device__ __forceinline__ void dma16(const void* g, void* l) {
    __builtin_amdgcn_global_load_lds(
        (const __attribute__((address_space(1))) void*)g,
        (__attribute__((address_space(3))) void*)l, 16, 0, 0);
}

// DPP row_ror butterfly: 4 stages -> every lane of a 16-lane row holds the row sum.
template <int CTRL>
__device__ __forceinline__ float dppadd(float x) {
    int v = __builtin_amdgcn_update_dpp(0, __builtin_bit_cast(int, x), CTRL, 0xf, 0xf, false);
    return x + __builtin_bit_cast(float, v);
}
__device__ __forceinline__ float rowsum16(float x) {
    x = dppadd<0x128>(x);
    x = dppadd<0x124>(x);
    x = dppadd<0x122>(x);
    x = dppadd<0x121>(x);
    return x;
}

// ---------------------------------------------------------------- LayerNorm
__global__ __launch_bounds__(256, 1) void k_ln(const float* __restrict__ x,
                                               const float* __restrict__ lnw,
                                               const float* __restrict__ lnb,
                                               unsigned short* __restrict__ xn) {
    const int m = blockIdx.x;
    const int t = threadIdx.x;
    float4 xv = ((const float4*)(x + (size_t)m * DMODEL))[t];
    float s = xv.x + xv.y + xv.z + xv.w;
    float s2 = xv.x * xv.x + xv.y * xv.y + xv.z * xv.z + xv.w * xv.w;
#pragma unroll
    for (int off = 32; off >= 1; off >>= 1) {
        s += __shfl_xor(s, off);
        s2 += __shfl_xor(s2, off);
    }
    __shared__ float red[8];
    const int wid = t >> 6;
    if ((t & 63) == 0) { red[wid] = s; red[4 + wid] = s2; }
    __syncthreads();
    if (t == 0) {
        float su = red[0] + red[1] + red[2] + red[3];
        float sq = red[4] + red[5] + red[6] + red[7];
        float mu = su * (1.f / DMODEL);
        float var = sq * (1.f / DMODEL) - mu * mu;
        red[0] = mu;
        red[1] = rsqrtf(var + 1e-5f);
    }
    __syncthreads();
    float mu = red[0], rstd = red[1];
    float4 w4 = ((const float4*)lnw)[t];
    float4 b4 = ((const float4*)lnb)[t];
    ushort4 o;
    o.x = f2bf((xv.x - mu) * rstd * w4.x + b4.x);
    o.y = f2bf((xv.y - mu) * rstd * w4.y + b4.y);
    o.z = f2bf((xv.z - mu) * rstd * w4.z + b4.z);
    o.w = f2bf((xv.w - mu) * rstd * w4.w + b4.w);
    ((ushort4*)(xn + (size_t)m * DMODEL))[t] = o;
}

// ------------------------------------------- fp32 -> bf16 weight conversion
struct WPtrs { const float* p0; const float* p1; const float* p2; const float* p3; const float* p4; };

__global__ __launch_bounds__(256, 1) void k_wconv(WPtrs w, unsigned short* __restrict__ dst) {
    const int plane = blockIdx.y;
    const float* src = plane == 0 ? w.p0 : plane == 1 ? w.p1 : plane == 2 ? w.p2
                                                             : plane == 3 ? w.p3 : w.p4;
    const size_t i = ((size_t)blockIdx.x * 256 + threadIdx.x) * 8;
    float4 f0 = *(const float4*)(src + i);
    float4 f1 = *(const float4*)(src + i + 4);
    uint4 o;
    o.x = (unsigned)f2bf(f0.x) | ((unsigned)f2bf(f0.y) << 16);
    o.y = (unsigned)f2bf(f0.z) | ((unsigned)f2bf(f0.w) << 16);
    o.z = (unsigned)f2bf(f1.x) | ((unsigned)f2bf(f1.y) << 16);
    o.w = (unsigned)f2bf(f1.z) | ((unsigned)f2bf(f1.w) << 16);
    *(uint4*)(dst + (size_t)plane * 1048576 + i) = o;
}

__global__ __launch_bounds__(256, 1) void k_cvt1(const float* __restrict__ src,
                                                 unsigned short* __restrict__ dst) {
    const size_t i = ((size_t)blockIdx.x * 256 + threadIdx.x) * 8;
    float4 f0 = *(const float4*)(src + i);
    float4 f1 = *(const float4*)(src + i + 4);
    uint4 o;
    o.x = (unsigned)f2bf(f0.x) | ((unsigned)f2bf(f0.y) << 16);
    o.y = (unsigned)f2bf(f0.z) | ((unsigned)f2bf(f0.w) << 16);
    o.z = (unsigned)f2bf(f1.x) | ((unsigned)f2bf(f1.y) << 16);
    o.w = (unsigned)f2bf(f1.z) | ((unsigned)f2bf(f1.w) << 16);
    *(uint4*)(dst + i) = o;
}

// ------------------------------------------------- 128x128 bf16 MFMA tile GEMM
template <int KDIM>
__device__ __forceinline__ void gemm128(const unsigned short* __restrict__ A,
                                        const unsigned short* __restrict__ Bw,
                                        int m0, int n0, f32x4 acc[4][4]) {
    __shared__ __align__(16) unsigned short sA[128 * 32];
    __shared__ __align__(16) unsigned short sB[128 * 32];

    const int t = threadIdx.x;
    const int lane = t & 63;
    const int wv = t >> 6;
    const int wm = wv >> 1, wn = wv & 1;
    const int ml = lane & 15, kq = lane >> 4;

#pragma unroll
    for (int i = 0; i < 4; i++)
#pragma unroll
        for (int j = 0; j < 4; j++) {
            f32x4 z; z[0] = 0.f; z[1] = 0.f; z[2] = 0.f; z[3] = 0.f;
            acc[i][j] = z;
        }

    const unsigned short* pA = A + (size_t)m0 * KDIM;
    const unsigned short* pB = Bw + (size_t)n0 * KDIM;
    const unsigned short* gA0 = pA + (size_t)(t >> 2) * KDIM + (t & 3) * 8;
    const unsigned short* gA1 = gA0 + (size_t)64 * KDIM;
    const unsigned short* gB0 = pB + (size_t)(t >> 2) * KDIM + (t & 3) * 8;
    const unsigned short* gB1 = gB0 + (size_t)64 * KDIM;
    unsigned short* lA0 = sA + wv * 512;
    unsigned short* lA1 = lA0 + 2048;
    unsigned short* lB0 = sB + wv * 512;
    unsigned short* lB1 = lB0 + 2048;

    for (int kb = 0; kb < KDIM / 32; kb++) {
        const int ko = kb * 32;
        dma16(gA0 + ko, lA0);
        dma16(gA1 + ko, lA1);
        dma16(gB0 + ko, lB0);
        dma16(gB1 + ko, lB1);
        __syncthreads();
        bf16x8 af[4], bfr[4];
#pragma unroll
        for (int mt = 0; mt < 4; mt++)
            af[mt] = *(const bf16x8*)&sA[(wm * 64 + mt * 16 + ml) * 32 + kq * 8];
#pragma unroll
        for (int nt = 0; nt < 4; nt++)
            bfr[nt] = *(const bf16x8*)&sB[(wn * 64 + nt * 16 + ml) * 32 + kq * 8];
#pragma unroll
        for (int mt = 0; mt < 4; mt++)
#pragma unroll
            for (int nt = 0; nt < 4; nt++)
                acc[mt][nt] = __builtin_amdgcn_mfma_f32_16x16x32_bf16(af[mt], bfr[nt], acc[mt][nt], 0, 0, 0);
        __syncthreads();
    }
}

// -------------------------------------------- fused 5-way projection GEMM
__global__ __launch_bounds__(256, 1) void k_proj(const unsigned short* __restrict__ xn,
                                                 const unsigned short* __restrict__ wbf,
                                                 const float* __restrict__ ba,
                                                 const float* __restrict__ baR,
                                                 __half* __restrict__ qo, __half* __restrict__ ko,
                                                 __half* __restrict__ vo, __half* __restrict__ ao,
                                                 __half* __restrict__ aRo) {
    const int m0 = blockIdx.x * 128;
    const int yt = blockIdx.y;
    const int widx = yt >> 3;
    const int n0 = (yt & 7) * 128;
    const unsigned short* W = wbf + (size_t)widx * 1048576;
    f32x4 acc[4][4];
    gemm128<1024>(xn, W, m0, n0, acc);

    __half* outp = widx == 0 ? qo : widx == 1 ? ko : widx == 2 ? vo : widx == 3 ? ao : aRo;
    const float* bias = (widx == 3) ? ba : (widx == 4) ? baR : (const float*)0;
    const int lane = threadIdx.x & 63;
    const int wv = threadIdx.x >> 6;
    const int wm = wv >> 1, wn = wv & 1;
    const int ml = lane & 15, kq = lane >> 4;
#pragma unroll
    for (int mt = 0; mt < 4; mt++)
#pragma unroll
        for (int nt = 0; nt < 4; nt++) {
            const int rowg = m0 + wm * 64 + mt * 16 + kq * 4;
            const int colg = n0 + wn * 64 + nt * 16 + ml;
            float bval = bias ? bias[colg] : 0.f;
#pragma unroll
            for (int r = 0; r < 4; r++) {
                float v = acc[mt][nt][r];
                if (widx >= 3) v = sigm(v + bval);
                outp[(size_t)(rowg + r) * DMODEL + colg] = __float2half(v);
            }
        }
}

// --------------------------------------------------- beta/gamma skinny GEMM
// writes interleaved float2 {beta,gamma} per (m,h)
__global__ __launch_bounds__(256, 1) void k_bg(const unsigned short* __restrict__ xn,
                                               const float* __restrict__ Wb,
                                               const float* __restrict__ bb,
                                               const float* __restrict__ Wg,
                                               const float* __restrict__ bgp,
                                               f32x2* __restrict__ bgpk) {
    const int m = blockIdx.x;
    const int t = threadIdx.x;
    const int h = t >> 4, seg = t & 15;
    const ushort4* xr = (const ushort4*)(xn + (size_t)m * DMODEL + seg * 64);
    const float4* wbr = (const float4*)(Wb + (size_t)h * DMODEL + seg * 64);
    const float4* wgr = (const float4*)(Wg + (size_t)h * DMODEL + seg * 64);
    float db = 0.f, dg = 0.f;
#pragma unroll
    for (int u = 0; u < 16; u++) {
        ushort4 a = xr[u];
        float4 w1 = wbr[u], w2 = wgr[u];
        union { unsigned int i; float f; } c0, c1, c2, c3;
        c0.i = ((unsigned int)a.x) << 16; c1.i = ((unsigned int)a.y) << 16;
        c2.i = ((unsigned int)a.z) << 16; c3.i = ((unsigned int)a.w) << 16;
        db += c0.f * w1.x + c1.f * w1.y + c2.f * w1.z + c3.f * w1.w;
        dg += c0.f * w2.x + c1.f * w2.y + c2.f * w2.z + c3.f * w2.w;
    }
#pragma unroll
    for (int off = 1; off < 16; off <<= 1) {
        db += __shfl_xor(db, off);
        dg += __shfl_xor(dg, off);
    }
    if (seg == 0) {
        f32x2 o;
        o[0] = sigm(db + bb[h]);
        o[1] = sigm(dg + bgp[h]);
        bgpk[(size_t)m * NH + h] = o;
    }
}

// ------------------------------------------- k normalization (in-place, fp16)
__global__ __launch_bounds__(256, 1) void k_prep(__half* __restrict__ kb) {
    const int row = blockIdx.x * 16 + (threadIdx.x >> 4);
    const int tr = threadIdx.x & 15;
    const int bh = row >> 11, t = row & 2047;
    const size_t idx = ((size_t)((bh >> 4) * T_SEQ + t)) * DMODEL + (bh & 15) * 64 + tr * 4;
    f16x4 k4 = *(const f16x4*)((const __half*)kb + idx);
    float k0 = (float)k4[0], k1 = (float)k4[1], k2 = (float)k4[2], k3 = (float)k4[3];
    float ss = k0 * k0 + k1 * k1 + k2 * k2 + k3 * k3;
    ss = rowsum16(ss);
    float inv = 1.f / fmaxf(sqrtf(ss), 1e-12f);
    f16x4 o;
    o[0] = (_Float16)(k0 * inv); o[1] = (_Float16)(k1 * inv);
    o[2] = (_Float16)(k2 * inv); o[3] = (_Float16)(k3 * inv);
    *(f16x4*)(kb + idx) = o;
}

// ------------------------------------------------------------- the scan
// 256 blocks; XCD-aware decode: bh = blk & 63, cg = blk >> 6. The 4 column-
// group blocks of one (b,h) sit at blk = bh + {0,64,128,192}; with round-robin
// XCD dispatch (xcd = blk % 8) and 64 % 8 == 0 they all land on the SAME XCD,
// so the shared kn/q/a/aR streams hit that XCD's L2 (~200 cyc) instead of
// 4 XCDs each missing to L3/HBM (~500-900 cyc).
// 6-slot register rotation as in round 5.
__global__ __launch_bounds__(256, 1) void k_scan(const __half* __restrict__ qb,
                                                 const __half* __restrict__ knb,
                                                 const __half* __restrict__ vb,
                                                 const __half* __restrict__ ab,
                                                 const __half* __restrict__ aRb,
                                                 const f32x2* __restrict__ bgpk,
                                                 unsigned short* __restrict__ ob) {
    const int blk = blockIdx.x;
    const int bh = blk & 63, cg = blk >> 6;   // XCD co-location swizzle
    const int b = bh >> 4, h = bh & 15;
    const int t = threadIdx.x;
    const int col = t >> 4, tr = t & 15;
    const int ii = cg * 16 + col;
    const int j0 = tr * 4;

    const size_t vecbase = ((size_t)b * T_SEQ) * DMODEL + h * 64 + j0;
    const size_t vbase = ((size_t)b * T_SEQ) * DMODEL + h * 64 + ii;
    const size_t bgbase = ((size_t)b * T_SEQ) * NH + h;

    const __half* pk = knb + vecbase;
    const __half* pq = qb + vecbase;
    const __half* pa = ab + vecbase;
    const __half* pr = aRb + vecbase;

    float S0 = 0, S1 = 0, S2 = 0, S3 = 0, R0 = 0, R1 = 0, R2 = 0, R3 = 0;

    f16x4 rk[6], rq[6], ra[6], rr[6];
    __half rv[6];
    f32x2 rbg[6];
    f32x4 fkn[6], fq[6], fa[6], fr[6];
    float fv[6];

#pragma unroll
    for (int p = 0; p < 6; p++) {
        const size_t voff = (size_t)p * DMODEL;
        rk[p] = *(const f16x4*)(pk + voff);
        rq[p] = *(const f16x4*)(pq + voff);
        ra[p] = *(const f16x4*)(pa + voff);
        rr[p] = *(const f16x4*)(pr + voff);
        rv[p] = vb[vbase + voff];
        rbg[p] = bgpk[bgbase + (size_t)p * NH];
    }
    fkn[0][0] = (float)rk[0][0]; fkn[0][1] = (float)rk[0][1]; fkn[0][2] = (float)rk[0][2]; fkn[0][3] = (float)rk[0][3];
    fq[0][0] = (float)rq[0][0]; fq[0][1] = (float)rq[0][1]; fq[0][2] = (float)rq[0][2]; fq[0][3] = (float)rq[0][3];
    fa[0][0] = (float)ra[0][0]; fa[0][1] = (float)ra[0][1]; fa[0][2] = (float)ra[0][2]; fa[0][3] = (float)ra[0][3];
    fr[0][0] = (float)rr[0][0]; fr[0][1] = (float)rr[0][1]; fr[0][2] = (float)rr[0][2]; fr[0][3] = (float)rr[0][3];
    fv[0] = (float)rv[0];

#define SCAN_BODY(P, PN)                                                              \
    {                                                                                 \
        const int s = st + (P);                                                       \
        const float beta = rbg[P][0], gamma = rbg[P][1];                              \
        /* prefetch step s+6 into slot P (its raw was cvt'd last body) */             \
        {                                                                             \
            const size_t voff = (size_t)((s + 6) & (T_SEQ - 1)) * DMODEL;             \
            rk[P] = *(const f16x4*)(pk + voff);                                       \
            rq[P] = *(const f16x4*)(pq + voff);                                       \
            ra[P] = *(const f16x4*)(pa + voff);                                       \
            rr[P] = *(const f16x4*)(pr + voff);                                       \
            rv[P] = vb[vbase + voff];                                                 \
        }                                                                             \
        /* cvt slot PN = step s+1 (loaded 5 bodies ago) */                            \
        fkn[PN][0] = (float)rk[PN][0]; fkn[PN][1] = (float)rk[PN][1];                 \
        fkn[PN][2] = (float)rk[PN][2]; fkn[PN][3] = (float)rk[PN][3];                 \
        fq[PN][0] = (float)rq[PN][0]; fq[PN][1] = (float)rq[PN][1];                   \
        fq[PN][2] = (float)rq[PN][2]; fq[PN][3] = (float)rq[PN][3];                   \
        fa[PN][0] = (float)ra[PN][0]; fa[PN][1] = (float)ra[PN][1];                   \
        fa[PN][2] = (float)ra[PN][2]; fa[PN][3] = (float)ra[PN][3];                   \
        fr[PN][0] = (float)rr[PN][0]; fr[PN][1] = (float)rr[PN][1];                   \
        fr[PN][2] = (float)rr[PN][2]; fr[PN][3] = (float)rr[PN][3];                   \
        fv[PN] = (float)rv[PN];                                                       \
        /* critical chain for step s, float set P */                                  \
        {                                                                             \
            const float kn0 = fkn[P][0], kn1 = fkn[P][1], kn2 = fkn[P][2], kn3 = fkn[P][3]; \
            const float a0 = fa[P][0], a1 = fa[P][1], a2 = fa[P][2], a3 = fa[P][3];   \
            const float x0 = fr[P][0], x1 = fr[P][1], x2 = fr[P][2], x3 = fr[P][3];   \
            const float vc = fv[P];                                                   \
            float pred = S0 * kn0 + S1 * kn1 + S2 * kn2 + S3 * kn3;                   \
            float Sd0 = a0 * S0, Sd1 = a1 * S1, Sd2 = a2 * S2, Sd3 = a3 * S3;         \
            float Rd0 = x0 * R0, Rd1 = x1 * R1, Rd2 = x2 * R2, Rd3 = x3 * R3;         \
            float kp = Sd0 * kn0 + Sd1 * kn1 + Sd2 * kn2 + Sd3 * kn3;                 \
            float kpR = Rd0 * kn0 + Rd1 * kn1 + Rd2 * kn2 + Rd3 * kn3;                \
            pred = rowsum16(pred);                                                    \
            kp = rowsum16(kp);                                                        \
            kpR = rowsum16(kpR);                                                      \
            const float rres = fminf(fmaxf(vc - pred, -1.f), 1.f);                    \
            const float cS = beta * (vc - kp);                                        \
            const float cR = gamma * (rres - kpR);                                    \
            S0 = fmaf(cS, kn0, Sd0); S1 = fmaf(cS, kn1, Sd1);                         \
            S2 = fmaf(cS, kn2, Sd2); S3 = fmaf(cS, kn3, Sd3);                         \
            R0 = fmaf(cR, kn0, Rd0); R1 = fmaf(cR, kn1, Rd1);                         \
            R2 = fmaf(cR, kn2, Rd2); R3 = fmaf(cR, kn3, Rd3);                         \
            float o = (S0 + R0) * fq[P][0] + (S1 + R1) * fq[P][1] +                   \
                      (S2 + R2) * fq[P][2] + (S3 + R3) * fq[P][3];                    \
            o = rowsum16(o);                                                          \
            if (tr == 0 && s < T_SEQ)                                                 \
                ob[vbase + (size_t)s * DMODEL] = f2bf(o);                             \
        }                                                                             \
        /* bg prefetch AFTER compute: rbg[P] consumed above, safe to overwrite */     \
        rbg[P] = bgpk[bgbase + (size_t)((s + 6) & (T_SEQ - 1)) * NH];                 \
    }

    for (int st = 0; st < T_SEQ; st += 6) {
        SCAN_BODY(0, 1)
        SCAN_BODY(1, 2)
        SCAN_BODY(2, 3)
        SCAN_BODY(3, 4)
        SCAN_BODY(4, 5)
        SCAN_BODY(5, 0)
    }
#undef SCAN_BODY
}

// ---------------------------------------------------- output GEMM + residual
__global__ __launch_bounds__(256, 1) void k_out(const unsigned short* __restrict__ ob,
                                                const unsigned short* __restrict__ wobf,
                                                const float* __restrict__ x,
                                                float* __restrict__ out) {
    const int m0 = blockIdx.x * 128;
    const int n0 = blockIdx.y * 128;
    f32x4 acc[4][4];
    gemm128<1024>(ob, wobf, m0, n0, acc);
    const int lane = threadIdx.x & 63;
    const int wv = threadIdx.x >> 6;
    const int wm = wv >> 1, wn = wv & 1;
    const int ml = lane & 15, kq = lane >> 4;
#pragma unroll
    for (int mt = 0; mt < 4; mt++)
#pragma unroll
        for (int nt = 0; nt < 4; nt++) {
            const int rowg = m0 + wm * 64 + mt * 16 + kq * 4;
            const int colg = n0 + wn * 64 + nt * 16 + ml;
#pragma unroll
            for (int r = 0; r < 4; r++) {
                size_t idx = (size_t)(rowg + r) * DMODEL + colg;
                out[idx] = acc[mt][nt][r] + x[idx];
            }
        }
}

extern "C" void kernel_launch(void* const* d_in, const int* in_sizes, int n_in,
                              void* d_out, int out_size, void* d_ws, size_t ws_size,
                              hipStream_t stream) {
    const float* x = (const float*)d_in[0];
    const float* Wq = (const float*)d_in[1];
    const float* Wk = (const float*)d_in[2];
    const float* Wv = (const float*)d_in[3];
    const float* Wa = (const float*)d_in[4];
    const float* ba = (const float*)d_in[5];
    const float* Wb = (const float*)d_in[6];
    const float* bb = (const float*)d_in[7];
    const float* Wg = (const float*)d_in[8];
    const float* bg = (const float*)d_in[9];
    const float* WaR = (const float*)d_in[10];
    const float* baR = (const float*)d_in[11];
    const float* Wo = (const float*)d_in[12];
    const float* lnw = (const float*)d_in[13];
    const float* lnb = (const float*)d_in[14];

    const size_t SZ = 16777216ULL;  // one fp16/bf16 plane (8192*1024*2 B)
    size_t need = 6 * SZ + 2 * 1048576ULL;
    if (ws_size < need) return;

    char* ws = (char*)d_ws;
    __half* qb = (__half*)(ws + 0 * SZ);
    __half* kb = (__half*)(ws + 1 * SZ);
    __half* vb = (__half*)(ws + 2 * SZ);
    __half* ab = (__half*)(ws + 3 * SZ);
    __half* aRb = (__half*)(ws + 4 * SZ);
    unsigned short* xn = (unsigned short*)(ws + 5 * SZ);  // bf16; reused for o
    f32x2* bgpk = (f32x2*)(ws + 6 * SZ);                   // 1 MB (+1 MB slack)

    // d_out doubles as scratch for bf16 projection weights (10 MB of 32 MB);
    // only read by k_proj, fully overwritten by k_out at the end.
    unsigned short* wbf = (unsigned short*)d_out;
    // Wo-bf16 goes into the (dead after scan) qb plane.
    unsigned short* wobf = (unsigned short*)qb;

    WPtrs wp{Wq, Wk, Wv, Wa, WaR};
    k_wconv<<<dim3(512, 5), dim3(256), 0, stream>>>(wp, wbf);
    k_ln<<<dim3(MTOT), dim3(256), 0, stream>>>(x, lnw, lnb, xn);
    k_proj<<<dim3(64, 40), dim3(256), 0, stream>>>(xn, wbf, ba, baR, qb, kb, vb, ab, aRb);
    k_bg<<<dim3(MTOT), dim3(256), 0, stream>>>(xn, Wb, bb, Wg, bg, bgpk);
    k_prep<<<dim3(MTOT * NH / 16), dim3(256), 0, stream>>>(kb);  // kb -> kn in place
    // scan writes o (bf16) over xn (xn dead after k_proj/k_bg)
    k_scan<<<dim3(256), dim3(256), 0, stream>>>(qb, kb, vb, ab, aRb, bgpk, xn);
    k_cvt1<<<dim3(512), dim3(256), 0, stream>>>(Wo, wobf);  // qb dead after scan
    k_out<<<dim3(64, 8), dim3(256), 0, stream>>>(xn, wobf, x, (float*)d_out);
}